// Round 1
// baseline (39.769 us; speedup 1.0000x reference)
//
#include <hip/hip_runtime.h>
#include <math.h>

namespace {
constexpr int NB   = 8;    // batch
constexpr int NWIN = 128;  // WIN
constexpr int NK   = 256;  // K (feature/attention dim)
constexpr int NE   = 256;  // E = 2*WIN

// ---------------------------------------------------------------------------
// Kernel 1: projections.
//   hi [b][i][e] = sum_w x[b][w][i] * W_lin[e][w]
//   hjT[b][e][j] = sum_w x[b][w][j] * W_lin[e][WIN+w] + b_lin[e]   (transposed!)
// grid = B * (E/8) = 256 blocks, 256 threads (thread = column index i/j).
// W reads are wave-uniform -> scalar loads; x reads are lane-coalesced.
// ---------------------------------------------------------------------------
__global__ __launch_bounds__(256) void k1_proj(
    const float* __restrict__ x, const float* __restrict__ W,
    const float* __restrict__ bl, float* __restrict__ hi,
    float* __restrict__ hjT)
{
  const int b  = blockIdx.x >> 5;
  const int e0 = (blockIdx.x & 31) << 3;
  const int i  = threadIdx.x;

  float acc1[8], acc2[8];
#pragma unroll
  for (int et = 0; et < 8; ++et) { acc1[et] = 0.f; acc2[et] = 0.f; }

  const float* xb = x + (size_t)b * NWIN * NK + i;
  const float* Wr = W + (size_t)e0 * (2 * NWIN);
#pragma unroll 4
  for (int w = 0; w < NWIN; ++w) {
    const float xv = xb[(size_t)w * NK];
#pragma unroll
    for (int et = 0; et < 8; ++et) {
      acc1[et] = fmaf(xv, Wr[et * 2 * NWIN + w], acc1[et]);
      acc2[et] = fmaf(xv, Wr[et * 2 * NWIN + NWIN + w], acc2[et]);
    }
  }

  float* hp = hi + ((size_t)(b * NK + i)) * NE + e0;   // 8 contiguous floats
#pragma unroll
  for (int et = 0; et < 8; ++et) hp[et] = acc1[et];
#pragma unroll
  for (int et = 0; et < 8; ++et)
    hjT[((size_t)(b * NE + e0 + et)) * NK + i] = acc2[et] + bl[e0 + et];
}

// ---------------------------------------------------------------------------
// Kernel 2: per (b, i-tile of 8) block, 512 threads.
//   e_ij = 0.25*(ai8_i + aj8_j) + sum_e a8_e*max(hi_ie + hjT_ej, 0) + bias_ij
//   attn = softmax_j(e_ij);  out[b][w][i] = sigmoid(sum_j attn_ij * x[b][w][j])
// where a8 = 0.8*a, ai8 = sum a8*hi_row, aj8 = sum a8*hjT_col (b_lin folded).
// grid = B * (K/8) = 256 blocks.
// ---------------------------------------------------------------------------
__global__ __launch_bounds__(512) void k2_attn(
    const float* __restrict__ x, const float* __restrict__ a_vec,
    const float* __restrict__ bias, const float* __restrict__ hi,
    const float* __restrict__ hjT, float* __restrict__ out)
{
  __shared__ float hi_lds[8][NE];      // 8 KB, read as wave-uniform broadcast
  __shared__ float a8_lds[NE];         // 1 KB
  __shared__ float sred[2][8][NK];     // 16 KB, e-half partial sums
  __shared__ float ajred[2][NK];       // 2 KB
  __shared__ float ai8_lds[8];
  __shared__ float attn[8][NK];        // 8 KB
  __shared__ float pvred[4][8][NWIN];  // 16 KB

  const int b    = blockIdx.x >> 5;
  const int i0   = (blockIdx.x & 31) << 3;
  const int t    = threadIdx.x;
  const int wave = t >> 6, lane = t & 63;

  // ---- stage hi tile + 0.8*a into LDS (coalesced) ----
  for (int idx = t; idx < 8 * NE; idx += 512) {
    const int ii = idx >> 8, e = idx & 255;
    hi_lds[ii][e] = hi[((size_t)(b * NK + i0 + ii)) * NE + e];
  }
  if (t < NE) a8_lds[t] = 0.8f * a_vec[t];
  __syncthreads();

  // ---- ai8 per row: wave q reduces row q ----
  {
    float p = 0.f;
#pragma unroll
    for (int r = 0; r < 4; ++r) {
      const int e = lane + r * 64;
      p = fmaf(a8_lds[e], hi_lds[wave][e], p);
    }
#pragma unroll
    for (int o = 32; o; o >>= 1) p += __shfl_xor(p, o);
    if (lane == 0) ai8_lds[wave] = p;
  }

  // ---- main relu-term loop: thread = (j, e-half) ----
  const int j = t & 255, half = t >> 8;
  float s[8];
#pragma unroll
  for (int ii = 0; ii < 8; ++ii) s[ii] = 0.f;
  float aj = 0.f;

  const float* hjb = hjT + (size_t)b * NE * NK + j;
  const int ebase = half * 128;
#pragma unroll 2
  for (int ec = 0; ec < 32; ++ec) {
    const int e = ebase + (ec << 2);
    const float h0 = hjb[(size_t)(e + 0) * NK];
    const float h1 = hjb[(size_t)(e + 1) * NK];
    const float h2 = hjb[(size_t)(e + 2) * NK];
    const float h3 = hjb[(size_t)(e + 3) * NK];
    const float4 a4 = *reinterpret_cast<const float4*>(&a8_lds[e]);
    aj = fmaf(a4.x, h0, aj); aj = fmaf(a4.y, h1, aj);
    aj = fmaf(a4.z, h2, aj); aj = fmaf(a4.w, h3, aj);
#pragma unroll
    for (int ii = 0; ii < 8; ++ii) {
      const float4 g = *reinterpret_cast<const float4*>(&hi_lds[ii][e]);
      s[ii] = fmaf(a4.x, fmaxf(g.x + h0, 0.f), s[ii]);
      s[ii] = fmaf(a4.y, fmaxf(g.y + h1, 0.f), s[ii]);
      s[ii] = fmaf(a4.z, fmaxf(g.z + h2, 0.f), s[ii]);
      s[ii] = fmaf(a4.w, fmaxf(g.w + h3, 0.f), s[ii]);
    }
  }
#pragma unroll
  for (int ii = 0; ii < 8; ++ii) sred[half][ii][j] = s[ii];
  ajred[half][j] = aj;
  __syncthreads();

  // ---- softmax over j: wave q handles row q ----
  {
    const int ii = wave;
    const float ai = ai8_lds[ii];
    float ev[4];
    float m = -INFINITY;
#pragma unroll
    for (int r = 0; r < 4; ++r) {
      const int jj = lane + r * 64;
      const float v = sred[0][ii][jj] + sred[1][ii][jj]
                    + 0.25f * (ai + ajred[0][jj] + ajred[1][jj])
                    + bias[(size_t)(i0 + ii) * NK + jj];
      ev[r] = v;
      m = fmaxf(m, v);
    }
#pragma unroll
    for (int o = 32; o; o >>= 1) m = fmaxf(m, __shfl_xor(m, o));
    float ssum = 0.f;
#pragma unroll
    for (int r = 0; r < 4; ++r) { ev[r] = __expf(ev[r] - m); ssum += ev[r]; }
#pragma unroll
    for (int o = 32; o; o >>= 1) ssum += __shfl_xor(ssum, o);
    const float inv = 1.f / ssum;
#pragma unroll
    for (int r = 0; r < 4; ++r) attn[ii][lane + r * 64] = ev[r] * inv;
  }
  __syncthreads();

  // ---- PV: out[b][w][i0+ii] = sigmoid(sum_j attn[ii][j] * x[b][w][j]) ----
  {
    const int w = t & 127, q = t >> 7;  // q = quarter of j-range
    float acc[8];
#pragma unroll
    for (int ii = 0; ii < 8; ++ii) acc[ii] = 0.f;
    const float* xr = x + (size_t)b * NWIN * NK + (size_t)w * NK + q * 64;
#pragma unroll 2
    for (int jc = 0; jc < 16; ++jc) {
      const float4 xv = *reinterpret_cast<const float4*>(&xr[jc * 4]);
#pragma unroll
      for (int ii = 0; ii < 8; ++ii) {
        const float4 at =
            *reinterpret_cast<const float4*>(&attn[ii][q * 64 + jc * 4]);
        acc[ii] = fmaf(at.x, xv.x, acc[ii]);
        acc[ii] = fmaf(at.y, xv.y, acc[ii]);
        acc[ii] = fmaf(at.z, xv.z, acc[ii]);
        acc[ii] = fmaf(at.w, xv.w, acc[ii]);
      }
    }
#pragma unroll
    for (int ii = 0; ii < 8; ++ii) pvred[q][ii][w] = acc[ii];
  }
  __syncthreads();

  if (t < NWIN) {
    const int w = t;
    float o[8];
#pragma unroll
    for (int ii = 0; ii < 8; ++ii) {
      const float v = pvred[0][ii][w] + pvred[1][ii][w] +
                      pvred[2][ii][w] + pvred[3][ii][w];
      o[ii] = 1.f / (1.f + __expf(-v));
    }
    float* op = out + ((size_t)(b * NWIN + w)) * NK + i0;
    *reinterpret_cast<float4*>(&op[0]) = make_float4(o[0], o[1], o[2], o[3]);
    *reinterpret_cast<float4*>(&op[4]) = make_float4(o[4], o[5], o[6], o[7]);
  }
}

}  // namespace

extern "C" void kernel_launch(void* const* d_in, const int* in_sizes, int n_in,
                              void* d_out, int out_size, void* d_ws,
                              size_t ws_size, hipStream_t stream)
{
  const float* x    = (const float*)d_in[0];  // (8,128,256)
  const float* Wlin = (const float*)d_in[1];  // (256,256)
  const float* blin = (const float*)d_in[2];  // (256,)
  const float* avec = (const float*)d_in[3];  // (256,1)
  const float* bias = (const float*)d_in[4];  // (256,256)
  float* out = (float*)d_out;                 // (8,128,256)

  float* hi  = (float*)d_ws;                       // B*K*E floats = 2 MB
  float* hjT = hi + (size_t)NB * NK * NE;          // B*E*K floats = 2 MB

  k1_proj<<<NB * (NE / 8), 256, 0, stream>>>(x, Wlin, blin, hi, hjT);
  k2_attn<<<NB * (NK / 8), 512, 0, stream>>>(x, avec, bias, hi, hjT, out);
}